// Round 5
// baseline (622.348 us; speedup 1.0000x reference)
//
#include <hip/hip_runtime.h>
#include <hip/hip_bf16.h>
#include <hip/hip_cooperative_groups.h>
#include <math.h>

namespace cg = cooperative_groups;

// ---------------------------------------------------------------------------
// FusionBlock_DenseAVInteractions — round 5: single cooperative mega-kernel.
// fp32 in/out, bf16 MFMA internal. Factorized attention (exact):
//   out[q] = softmax_i(Sv)@Vv + softmax_j(Sa)@Va
//
// Round-4 post-mortem: all 8 kernels < 42 us each; dur 202 us >> sum of
// roofline estimates (~70 us). Diagnosis: ~10 us/launch overhead x 8.
// Fix: 1 cooperative launch, 7 grid.sync()s, phases grid-stride.
// 512 blocks x 256 thr, __launch_bounds__(256,2) -> 2 blocks/CU resident.
// ---------------------------------------------------------------------------

typedef unsigned short ushort_t;
typedef __attribute__((ext_vector_type(8))) __bf16 bf16x8;
typedef __attribute__((ext_vector_type(4))) float f32x4;

#define DEVFN static __device__ __forceinline__

DEVFN float bf2f(ushort_t u) {
    return __uint_as_float(((unsigned int)u) << 16);
}
DEVFN ushort_t f2bf(float f) {
    unsigned int x = __float_as_uint(f);
    unsigned int r = x + 0x7FFFu + ((x >> 16) & 1u);  // RNE
    return (ushort_t)(r >> 16);
}
DEVFN void unpack8(uint4 dv, float* dst) {
    unsigned int ws[4] = {dv.x, dv.y, dv.z, dv.w};
#pragma unroll
    for (int i = 0; i < 4; i++) {
        dst[2 * i] = __uint_as_float(ws[i] << 16);
        dst[2 * i + 1] = __uint_as_float(ws[i] & 0xFFFF0000u);
    }
}

struct MegaParams {
    // inputs
    const float *xmm, *xv, *xa;
    const float *ln_mm_w, *ln_mm_b, *ln_v_w, *ln_v_b, *ln_a_w, *ln_a_b;
    const float *Wq, *Wkv, *Wproj, *bproj, *ln_mlp_w, *ln_mlp_b;
    const float *W1, *b1, *W2, *b2;
    float* outp;
    // workspace
    ushort_t *xmmN, *xvN, *xaN;
    ushort_t *Wqt, *Wkvt, *Wprojt, *W1t, *W2t;
    ushort_t *qout, *kvvb, *kvab, *attnout;
    float* y;
    ushort_t *h0, *g;
    float* P;
};

// ---------------------------------------------------------------------------
// LayerNorm body: 256 threads, one row of 1024. fp32 in -> bf16 out.
// ---------------------------------------------------------------------------
DEVFN void ln_body(const float* __restrict__ x, const float* __restrict__ w,
                   const float* __restrict__ b, ushort_t* __restrict__ out,
                   int row, float* red) {
    const float4* xr4 = (const float4*)(x + (size_t)row * 1024);
    ushort_t* orow = out + (size_t)row * 1024;
    int tid = threadIdx.x;
    float4 v4 = xr4[tid];
    float s = v4.x + v4.y + v4.z + v4.w;
    float ss = v4.x * v4.x + v4.y * v4.y + v4.z * v4.z + v4.w * v4.w;
#pragma unroll
    for (int off = 32; off > 0; off >>= 1) {
        s += __shfl_down(s, off);
        ss += __shfl_down(ss, off);
    }
    if ((tid & 63) == 0) {
        red[tid >> 6] = s;
        red[4 + (tid >> 6)] = ss;
    }
    __syncthreads();
    s = red[0] + red[1] + red[2] + red[3];
    ss = red[4] + red[5] + red[6] + red[7];
    float mean = s * (1.f / 1024.f);
    float var = ss * (1.f / 1024.f) - mean * mean;
    float rstd = rsqrtf(var + 1e-5f);
    const float4 w4 = ((const float4*)w)[tid];
    const float4 b4 = ((const float4*)b)[tid];
    union { ushort_t u[4]; uint2 v; } pk;
    pk.u[0] = f2bf((v4.x - mean) * rstd * w4.x + b4.x);
    pk.u[1] = f2bf((v4.y - mean) * rstd * w4.y + b4.y);
    pk.u[2] = f2bf((v4.z - mean) * rstd * w4.z + b4.z);
    pk.u[3] = f2bf((v4.w - mean) * rstd * w4.w + b4.w);
    *(uint2*)(&orow[tid * 4]) = pk.v;
}

// ---------------------------------------------------------------------------
// Pipelined MFMA bf16 GEMM item: 64x64 tile, BK=32, 256 threads (2x2 waves).
// EPI: 0 bf16 store; 2 +bias +exact GELU bf16; 3 +bias +resid fp32;
//      4 raw fp32 store (split-K partial)
// ---------------------------------------------------------------------------
template <int EPI, typename OutT>
DEVFN void gemm_item(const ushort_t* __restrict__ A, int lda,
                     const ushort_t* __restrict__ B, int ldb,
                     OutT* __restrict__ C, int ldc,
                     const float* __restrict__ bias,
                     const float* __restrict__ resid, int K, int m0, int n0,
                     ushort_t* As, ushort_t* Bs) {
    constexpr int LS = 40;
    int tid = threadIdx.x;
    int wave = tid >> 6, lane = tid & 63;
    int wm = wave >> 1, wn = wave & 1;
    int quad = lane >> 4, l16 = lane & 15;

    f32x4 acc[2][2];
#pragma unroll
    for (int i = 0; i < 2; i++)
#pragma unroll
        for (int j = 0; j < 2; j++) acc[i][j] = (f32x4){0.f, 0.f, 0.f, 0.f};

    int r = tid >> 2, c = tid & 3;
    const ushort_t* Ap = A + (size_t)(m0 + r) * lda + c * 8;
    const ushort_t* Bp = B + (size_t)(n0 + r) * ldb + c * 8;
    uint4 ra = *(const uint4*)Ap;
    uint4 rb = *(const uint4*)Bp;

    for (int k0 = 0; k0 < K; k0 += 32) {
        *(uint4*)(&As[r * LS + c * 8]) = ra;
        *(uint4*)(&Bs[r * LS + c * 8]) = rb;
        __syncthreads();
        if (k0 + 32 < K) {
            ra = *(const uint4*)(Ap + k0 + 32);
            rb = *(const uint4*)(Bp + k0 + 32);
        }
        bf16x8 af[2], bfr[2];
#pragma unroll
        for (int i = 0; i < 2; i++)
            af[i] = *(const bf16x8*)(&As[(wm * 32 + i * 16 + l16) * LS + quad * 8]);
#pragma unroll
        for (int j = 0; j < 2; j++)
            bfr[j] = *(const bf16x8*)(&Bs[(wn * 32 + j * 16 + l16) * LS + quad * 8]);
#pragma unroll
        for (int i = 0; i < 2; i++)
#pragma unroll
            for (int j = 0; j < 2; j++)
                acc[i][j] = __builtin_amdgcn_mfma_f32_16x16x32_bf16(
                    af[i], bfr[j], acc[i][j], 0, 0, 0);
        __syncthreads();  // also protects LDS for the next grid-stride item
    }

#pragma unroll
    for (int i = 0; i < 2; i++)
#pragma unroll
        for (int j = 0; j < 2; j++) {
            int col = n0 + wn * 32 + j * 16 + l16;
            int rbase = m0 + wm * 32 + i * 16 + quad * 4;
            float bv = (EPI == 2 || EPI == 3) ? bias[col] : 0.f;
#pragma unroll
            for (int rr = 0; rr < 4; rr++) {
                int row = rbase + rr;
                float vv = acc[i][j][rr] + bv;
                if (EPI == 2) vv = 0.5f * vv * (1.f + erff(vv * 0.70710678118654752f));
                if (EPI == 3) vv += resid[(size_t)row * ldc + col];
                if constexpr (sizeof(OutT) == 2)
                    C[(size_t)row * ldc + col] = (OutT)f2bf(vv);
                else
                    C[(size_t)row * ldc + col] = vv;
            }
        }
}

// ---------------------------------------------------------------------------
// The mega-kernel. 512 blocks x 256 threads, cooperative.
// ---------------------------------------------------------------------------
__global__ __launch_bounds__(256, 2) void mega_kernel(MegaParams p) {
    cg::grid_group grid = cg::this_grid();
    __shared__ alignas(16) unsigned char smem[24576];
    int tid = threadIdx.x;
    int nb = gridDim.x;

    // ---- P0: 3 LayerNorms (items 0..895) + 5 weight transposes ----
    {
        float* red = (float*)smem;
        ushort_t* tile = (ushort_t*)smem;  // 32x33 bf16 = 2112 B
        for (int t = blockIdx.x; t < 896 + 9728; t += nb) {
            if (t < 896) {
                const float *x, *w, *b; ushort_t* o; int start;
                if (t >= 640)      { x = p.xa;  w = p.ln_a_w;  b = p.ln_a_b;  o = p.xaN;  start = 640; }
                else if (t >= 512) { x = p.xv;  w = p.ln_v_w;  b = p.ln_v_b;  o = p.xvN;  start = 512; }
                else               { x = p.xmm; w = p.ln_mm_w; b = p.ln_mm_b; o = p.xmmN; start = 0; }
                ln_body(x, w, b, o, t - start, red);
            } else {
                int id = t - 896;
                const float* in; ushort_t* out; int R, C, nx, start;
                if (id >= 5632)      { in = p.W2;    out = p.W2t;    R = 4096; C = 1024; nx = 32;  start = 5632; }
                else if (id >= 1536) { in = p.W1;    out = p.W1t;    R = 1024; C = 4096; nx = 128; start = 1536; }
                else if (id >= 1280) { in = p.Wproj; out = p.Wprojt; R = 256;  C = 1024; nx = 32;  start = 1280; }
                else if (id >= 256)  { in = p.Wkv;   out = p.Wkvt;   R = 2048; C = 512;  nx = 16;  start = 256; }
                else                 { in = p.Wq;    out = p.Wqt;    R = 1024; C = 256;  nx = 8;   start = 0; }
                int tt = id - start;
                int bx = (tt % nx) * 32;
                int by = (tt / nx) * 32;
                // stage: thread reads float4 (row r, cols c4..c4+3)
                int r = tid >> 3, c4 = (tid & 7) * 4;
                float4 f = *(const float4*)(in + (size_t)(by + r) * C + bx + c4);
                ushort_t* tr = tile + r * 33 + c4;
                tr[0] = f2bf(f.x); tr[1] = f2bf(f.y);
                tr[2] = f2bf(f.z); tr[3] = f2bf(f.w);
                __syncthreads();
                // write: out row (bx+oc), cols (by+or4..+3) = tile[or4+j][oc]
                int oc = tid >> 3, or4 = (tid & 7) * 4;
                union { ushort_t u[4]; uint2 v; } pk;
#pragma unroll
                for (int j = 0; j < 4; j++) pk.u[j] = tile[(or4 + j) * 33 + oc];
                *(uint2*)(out + (size_t)(bx + oc) * R + by + or4) = pk.v;
            }
            __syncthreads();
        }
    }
    grid.sync();

    // ---- P1: q / kv_v / kv_a projections (80 tiles, K=1024) ----
    {
        ushort_t* As = (ushort_t*)smem;
        ushort_t* Bs = As + 64 * 40;
        for (int t = blockIdx.x; t < 80; t += nb) {
            const ushort_t *A, *B; ushort_t* C; int lda, ldb, ldc, nx, start;
            if (t >= 48)      { A = p.xaN;  B = p.Wkvt + 1024; C = p.kvab; lda = 1024; ldb = 2048; ldc = 512; nx = 8; start = 48; }
            else if (t >= 32) { A = p.xvN;  B = p.Wkvt;        C = p.kvvb; lda = 1024; ldb = 2048; ldc = 512; nx = 8; start = 32; }
            else              { A = p.xmmN; B = p.Wqt;         C = p.qout; lda = 1024; ldb = 1024; ldc = 256; nx = 4; start = 0; }
            int tt = t - start;
            gemm_item<0, ushort_t>(A, lda, B, ldb, C, ldc, nullptr, nullptr,
                                   1024, (tt / nx) * 64, (tt % nx) * 64, As, Bs);
        }
    }
    grid.sync();

    // ---- P2: factorized attention (128 items) ----
    {
        float* Kv = (float*)smem;          // [64][16]
        float* Vv = Kv + 64 * 16;
        float* Ka = Vv + 64 * 16;          // [128][16]
        float* Va = Ka + 128 * 16;
        for (int t = blockIdx.x; t < 128; t += nb) {
            int bh = t & 31, qc = t >> 5;
            int b = bh >> 4, h = bh & 15;
            {
                int row = tid >> 2, seg = (tid >> 1) & 1, half = tid & 1;
                const ushort_t* src = p.kvvb + (size_t)(b * 64 + row) * 512 +
                                      seg * 256 + h * 16 + half * 8;
                float* dst = (seg ? Vv : Kv) + row * 16 + half * 8;
                unpack8(*(const uint4*)src, dst);
            }
#pragma unroll
            for (int t2 = 0; t2 < 2; t2++) {
                int tt = tid + t2 * 256;
                int row = tt >> 2, seg = (tt >> 1) & 1, half = tt & 1;
                const ushort_t* src = p.kvab + (size_t)(b * 128 + row) * 512 +
                                      seg * 256 + h * 16 + half * 8;
                float* dst = (seg ? Va : Ka) + row * 16 + half * 8;
                unpack8(*(const uint4*)src, dst);
            }
            __syncthreads();

            int qlocal = tid >> 2;
            int dg = tid & 3;
            int qrow = qc * 64 + qlocal;
            const ushort_t* qp =
                p.qout + (size_t)(b * 256 + qrow) * 256 + h * 16 + dg * 4;
            uint2 qu = *(const uint2*)qp;
            float4 qv;
            qv.x = __uint_as_float(qu.x << 16) * 0.125f;
            qv.y = __uint_as_float(qu.x & 0xFFFF0000u) * 0.125f;
            qv.z = __uint_as_float(qu.y << 16) * 0.125f;
            qv.w = __uint_as_float(qu.y & 0xFFFF0000u) * 0.125f;

            const float4* Kv4 = (const float4*)Kv;
            const float4* Vv4 = (const float4*)Vv;
            const float4* Ka4 = (const float4*)Ka;
            const float4* Va4 = (const float4*)Va;

            float4 ov = {0.f, 0.f, 0.f, 0.f};
            float den = 0.f;
#pragma unroll 8
            for (int i = 0; i < 64; i++) {
                float4 kk = Kv4[i * 4 + dg];
                float part = qv.x * kk.x + qv.y * kk.y + qv.z * kk.z + qv.w * kk.w;
                part += __shfl_xor(part, 1);
                part += __shfl_xor(part, 2);
                float pe = __expf(part);
                den += pe;
                float4 vv = Vv4[i * 4 + dg];
                ov.x += pe * vv.x; ov.y += pe * vv.y;
                ov.z += pe * vv.z; ov.w += pe * vv.w;
            }
            float4 oa = {0.f, 0.f, 0.f, 0.f};
            float dena = 0.f;
#pragma unroll 8
            for (int i = 0; i < 128; i++) {
                float4 kk = Ka4[i * 4 + dg];
                float part = qv.x * kk.x + qv.y * kk.y + qv.z * kk.z + qv.w * kk.w;
                part += __shfl_xor(part, 1);
                part += __shfl_xor(part, 2);
                float pe = __expf(part);
                dena += pe;
                float4 vv = Va4[i * 4 + dg];
                oa.x += pe * vv.x; oa.y += pe * vv.y;
                oa.z += pe * vv.z; oa.w += pe * vv.w;
            }

            float rv = 1.f / den, ra = 1.f / dena;
            union { ushort_t u[4]; uint2 v; } pk;
            pk.u[0] = f2bf(ov.x * rv + oa.x * ra);
            pk.u[1] = f2bf(ov.y * rv + oa.y * ra);
            pk.u[2] = f2bf(ov.z * rv + oa.z * ra);
            pk.u[3] = f2bf(ov.w * rv + oa.w * ra);
            *(uint2*)(p.attnout + (size_t)(b * 256 + qrow) * 256 + h * 16 +
                      dg * 4) = pk.v;
            __syncthreads();
        }
    }
    grid.sync();

    // ---- P3: y = attnout @ Wproj + bproj + xmm (128 tiles, K=256) ----
    {
        ushort_t* As = (ushort_t*)smem;
        ushort_t* Bs = As + 64 * 40;
        for (int t = blockIdx.x; t < 128; t += nb)
            gemm_item<3, float>(p.attnout, 256, p.Wprojt, 256, p.y, 1024,
                                p.bproj, p.xmm, 256, (t >> 4) * 64,
                                (t & 15) * 64, As, Bs);
    }
    grid.sync();

    // ---- P4: h0 = LN(y) (512 rows) ----
    {
        float* red = (float*)smem;
        for (int t = blockIdx.x; t < 512; t += nb) {
            ln_body(p.y, p.ln_mlp_w, p.ln_mlp_b, p.h0, t, red);
            __syncthreads();
        }
    }
    grid.sync();

    // ---- P5: g = gelu(h0 @ W1 + b1) (512 tiles, K=1024) ----
    {
        ushort_t* As = (ushort_t*)smem;
        ushort_t* Bs = As + 64 * 40;
        for (int t = blockIdx.x; t < 512; t += nb)
            gemm_item<2, ushort_t>(p.h0, 1024, p.W1t, 1024, p.g, 4096, p.b1,
                                   nullptr, 1024, (t >> 6) * 64, (t & 63) * 64,
                                   As, Bs);
    }
    grid.sync();

    // ---- P6: split-K=4 partials P[z] = g @ W2 slice (512 tiles, K=1024) ----
    {
        ushort_t* As = (ushort_t*)smem;
        ushort_t* Bs = As + 64 * 40;
        for (int t = blockIdx.x; t < 512; t += nb) {
            int z = t >> 7, rem = t & 127;
            gemm_item<4, float>(p.g + z * 1024, 4096, p.W2t + z * 1024, 4096,
                                p.P + (size_t)z * 512 * 1024, 1024, nullptr,
                                nullptr, 1024, (rem >> 4) * 64, (rem & 15) * 64,
                                As, Bs);
        }
    }
    grid.sync();

    // ---- P7: out = sum_z P[z] + b2 + y ----
    {
        for (int t = blockIdx.x; t < 512; t += nb) {
            int i = t * 256 + tid;
            const float4* pp = (const float4*)p.P;
            float4 a = pp[i], b = pp[i + 131072], cc = pp[i + 2 * 131072],
                   d = pp[i + 3 * 131072];
            float4 yy = ((const float4*)p.y)[i];
            float4 bb = ((const float4*)p.b2)[i & 255];
            float4 o;
            o.x = a.x + b.x + cc.x + d.x + yy.x + bb.x;
            o.y = a.y + b.y + cc.y + d.y + yy.y + bb.y;
            o.z = a.z + b.z + cc.z + d.z + yy.z + bb.z;
            o.w = a.w + b.w + cc.w + d.w + yy.w + bb.w;
            ((float4*)p.outp)[i] = o;
        }
    }
}

// ---------------------------------------------------------------------------
extern "C" void kernel_launch(void* const* d_in, const int* in_sizes, int n_in,
                              void* d_out, int out_size, void* d_ws,
                              size_t ws_size, hipStream_t stream) {
    MegaParams p;
    p.xmm = (const float*)d_in[0];
    p.xv = (const float*)d_in[1];
    p.xa = (const float*)d_in[2];
    p.ln_mm_w = (const float*)d_in[3];
    p.ln_mm_b = (const float*)d_in[4];
    p.ln_v_w = (const float*)d_in[5];
    p.ln_v_b = (const float*)d_in[6];
    p.ln_a_w = (const float*)d_in[7];
    p.ln_a_b = (const float*)d_in[8];
    p.Wq = (const float*)d_in[9];
    p.Wkv = (const float*)d_in[10];
    p.Wproj = (const float*)d_in[11];
    p.bproj = (const float*)d_in[12];
    p.ln_mlp_w = (const float*)d_in[13];
    p.ln_mlp_b = (const float*)d_in[14];
    p.W1 = (const float*)d_in[15];
    p.b1 = (const float*)d_in[16];
    p.W2 = (const float*)d_in[17];
    p.b2 = (const float*)d_in[18];
    p.outp = (float*)d_out;

    char* w = (char*)d_ws;
    p.xmmN = (ushort_t*)w;    w += 512 * 1024 * 2;
    p.xvN = (ushort_t*)w;     w += 128 * 1024 * 2;
    p.xaN = (ushort_t*)w;     w += 256 * 1024 * 2;
    p.Wqt = (ushort_t*)w;     w += 256 * 1024 * 2;
    p.Wkvt = (ushort_t*)w;    w += 512 * 2048 * 2;
    p.Wprojt = (ushort_t*)w;  w += 1024 * 256 * 2;
    p.W1t = (ushort_t*)w;     w += 4096 * 1024 * 2;
    p.W2t = (ushort_t*)w;     w += 1024 * 4096 * 2;
    p.qout = (ushort_t*)w;    w += 512 * 256 * 2;
    p.kvvb = (ushort_t*)w;    w += 128 * 512 * 2;
    p.kvab = (ushort_t*)w;    w += 256 * 512 * 2;
    p.attnout = (ushort_t*)w; w += 512 * 256 * 2;
    p.y = (float*)w;          w += 512 * 1024 * 4;
    p.h0 = (ushort_t*)w;      w += 512 * 1024 * 2;
    p.g = (ushort_t*)w;       w += 512 * 4096 * 2;
    p.P = (float*)w;          w += 4 * 512 * 1024 * 4;

    void* kargs[] = {(void*)&p};
    hipLaunchCooperativeKernel((void*)mega_kernel, dim3(512), dim3(256), kargs,
                               0, stream);

    (void)in_sizes; (void)n_in; (void)out_size; (void)ws_size;
}

// Round 6
// 204.862 us; speedup vs baseline: 3.0379x; 3.0379x over previous
//
#include <hip/hip_runtime.h>
#include <hip/hip_bf16.h>
#include <math.h>

// ---------------------------------------------------------------------------
// FusionBlock_DenseAVInteractions — round 6
// fp32 in/out, bf16 MFMA internal. Factorized attention (exact):
//   out[q] = softmax_i(Sv)@Vv + softmax_j(Sa)@Va
//
// Round-5 post-mortem: cooperative mega-kernel = 622 us; grid.sync() costs
// ~56 us each on 8-XCD MI355X (spin shows as idle VALU). Reverted to
// multi-launch (round-4 = 202 us) and fused WITHOUT grid sync:
//  * LN(y) folded into mlp1 A-staging via per-row sum/sumsq atomics
//    accumulated in the proj epilogue (removes ln launch + h0 buffer).
//  * mlp2 split-K partials atomicAdd directly into outp, which proj
//    pre-initializes to y + b2 (removes reduce launch + P buffer).
// 6 launches: prep -> qkv -> attn -> proj -> mlp1 -> mlp2.
// ---------------------------------------------------------------------------

typedef unsigned short ushort_t;
typedef __attribute__((ext_vector_type(8))) __bf16 bf16x8;
typedef __attribute__((ext_vector_type(4))) float f32x4;

#define DEVFN static __device__ __forceinline__

DEVFN float bf2f(ushort_t u) {
    return __uint_as_float(((unsigned int)u) << 16);
}
DEVFN ushort_t f2bf(float f) {
    unsigned int x = __float_as_uint(f);
    unsigned int r = x + 0x7FFFu + ((x >> 16) & 1u);  // RNE
    return (ushort_t)(r >> 16);
}
DEVFN void unpack8(uint4 dv, float* dst) {
    unsigned int ws[4] = {dv.x, dv.y, dv.z, dv.w};
#pragma unroll
    for (int i = 0; i < 4; i++) {
        dst[2 * i] = __uint_as_float(ws[i] << 16);
        dst[2 * i + 1] = __uint_as_float(ws[i] & 0xFFFF0000u);
    }
}

struct LNSeg {
    const float* x; const float* w; const float* b; ushort_t* out; int start;
};
struct TDesc { const float* in; ushort_t* out; int R, C, nx, start; };

// ---------------------------------------------------------------------------
// Prep: blocks [0,896) = 3 input LayerNorms (fp32 -> bf16);
//       blocks [896, 896+9728) = 5 weight transpose+casts (fp32[R,C]->bf16[C,R])
//       block 0 additionally zeroes the 1024-float stats buffer.
// ---------------------------------------------------------------------------
__global__ __launch_bounds__(256) void prep_kernel(LNSeg l0, LNSeg l1,
                                                   LNSeg l2, TDesc d0,
                                                   TDesc d1, TDesc d2,
                                                   TDesc d3, TDesc d4,
                                                   float* stats) {
    int id = blockIdx.x;
    int tid = threadIdx.x;
    if (id == 0) ((float4*)stats)[tid] = (float4){0.f, 0.f, 0.f, 0.f};

    if (id < 896) {
        const float *x, *w, *b; ushort_t* o; int start;
        if (id >= l2.start)      { x = l2.x; w = l2.w; b = l2.b; o = l2.out; start = l2.start; }
        else if (id >= l1.start) { x = l1.x; w = l1.w; b = l1.b; o = l1.out; start = l1.start; }
        else                     { x = l0.x; w = l0.w; b = l0.b; o = l0.out; start = 0; }
        int row = id - start;
        const float4* xr4 = (const float4*)(x + (size_t)row * 1024);
        float4 v4 = xr4[tid];
        float s = v4.x + v4.y + v4.z + v4.w;
        float ss = v4.x * v4.x + v4.y * v4.y + v4.z * v4.z + v4.w * v4.w;
#pragma unroll
        for (int off = 32; off > 0; off >>= 1) {
            s += __shfl_down(s, off);
            ss += __shfl_down(ss, off);
        }
        __shared__ float red[8];
        if ((tid & 63) == 0) {
            red[tid >> 6] = s;
            red[4 + (tid >> 6)] = ss;
        }
        __syncthreads();
        s = red[0] + red[1] + red[2] + red[3];
        ss = red[4] + red[5] + red[6] + red[7];
        float mean = s * (1.f / 1024.f);
        float var = ss * (1.f / 1024.f) - mean * mean;
        float rstd = rsqrtf(var + 1e-5f);
        const float4 w4 = ((const float4*)w)[tid];
        const float4 b4 = ((const float4*)b)[tid];
        union { ushort_t u[4]; uint2 v; } pk;
        pk.u[0] = f2bf((v4.x - mean) * rstd * w4.x + b4.x);
        pk.u[1] = f2bf((v4.y - mean) * rstd * w4.y + b4.y);
        pk.u[2] = f2bf((v4.z - mean) * rstd * w4.z + b4.z);
        pk.u[3] = f2bf((v4.w - mean) * rstd * w4.w + b4.w);
        *(uint2*)(o + (size_t)row * 1024 + tid * 4) = pk.v;
        return;
    }

    int t = id - 896;
    const float* in; ushort_t* out; int R, C, nx, start;
    if (t >= d4.start)      { in = d4.in; out = d4.out; R = d4.R; C = d4.C; nx = d4.nx; start = d4.start; }
    else if (t >= d3.start) { in = d3.in; out = d3.out; R = d3.R; C = d3.C; nx = d3.nx; start = d3.start; }
    else if (t >= d2.start) { in = d2.in; out = d2.out; R = d2.R; C = d2.C; nx = d2.nx; start = d2.start; }
    else if (t >= d1.start) { in = d1.in; out = d1.out; R = d1.R; C = d1.C; nx = d1.nx; start = d1.start; }
    else                    { in = d0.in; out = d0.out; R = d0.R; C = d0.C; nx = d0.nx; start = 0; }
    int tt = t - start;
    int bx = (tt % nx) * 32;
    int by = (tt / nx) * 32;
    __shared__ ushort_t tile[32 * 33];
    int r = tid >> 3, c4 = (tid & 7) * 4;
    float4 f = *(const float4*)(in + (size_t)(by + r) * C + bx + c4);
    ushort_t* tr = tile + r * 33 + c4;
    tr[0] = f2bf(f.x); tr[1] = f2bf(f.y); tr[2] = f2bf(f.z); tr[3] = f2bf(f.w);
    __syncthreads();
    int oc = tid >> 3, or4 = (tid & 7) * 4;
    union { ushort_t u[4]; uint2 v; } pk;
#pragma unroll
    for (int j = 0; j < 4; j++) pk.u[j] = tile[(or4 + j) * 33 + oc];
    *(uint2*)(out + (size_t)(bx + oc) * R + by + or4) = pk.v;
}

// ---------------------------------------------------------------------------
// Pipelined MFMA bf16 GEMM item: 64x64 tile, BK=32, 256 threads (2x2 waves).
// EPI: 0 = bf16 store; 5 = fp32 atomicAdd into C (split-K accumulate)
// ---------------------------------------------------------------------------
template <int EPI, typename OutT>
DEVFN void gemm_item(const ushort_t* __restrict__ A, int lda,
                     const ushort_t* __restrict__ B, int ldb,
                     OutT* __restrict__ C, int ldc, int K, int m0, int n0,
                     ushort_t* As, ushort_t* Bs) {
    constexpr int LS = 40;
    int tid = threadIdx.x;
    int wave = tid >> 6, lane = tid & 63;
    int wm = wave >> 1, wn = wave & 1;
    int quad = lane >> 4, l16 = lane & 15;

    f32x4 acc[2][2];
#pragma unroll
    for (int i = 0; i < 2; i++)
#pragma unroll
        for (int j = 0; j < 2; j++) acc[i][j] = (f32x4){0.f, 0.f, 0.f, 0.f};

    int r = tid >> 2, c = tid & 3;
    const ushort_t* Ap = A + (size_t)(m0 + r) * lda + c * 8;
    const ushort_t* Bp = B + (size_t)(n0 + r) * ldb + c * 8;
    uint4 ra = *(const uint4*)Ap;
    uint4 rb = *(const uint4*)Bp;

    for (int k0 = 0; k0 < K; k0 += 32) {
        *(uint4*)(&As[r * LS + c * 8]) = ra;
        *(uint4*)(&Bs[r * LS + c * 8]) = rb;
        __syncthreads();
        if (k0 + 32 < K) {
            ra = *(const uint4*)(Ap + k0 + 32);
            rb = *(const uint4*)(Bp + k0 + 32);
        }
        bf16x8 af[2], bfr[2];
#pragma unroll
        for (int i = 0; i < 2; i++)
            af[i] = *(const bf16x8*)(&As[(wm * 32 + i * 16 + l16) * LS + quad * 8]);
#pragma unroll
        for (int j = 0; j < 2; j++)
            bfr[j] = *(const bf16x8*)(&Bs[(wn * 32 + j * 16 + l16) * LS + quad * 8]);
#pragma unroll
        for (int i = 0; i < 2; i++)
#pragma unroll
            for (int j = 0; j < 2; j++)
                acc[i][j] = __builtin_amdgcn_mfma_f32_16x16x32_bf16(
                    af[i], bfr[j], acc[i][j], 0, 0, 0);
        __syncthreads();
    }

#pragma unroll
    for (int i = 0; i < 2; i++)
#pragma unroll
        for (int j = 0; j < 2; j++) {
            int col = n0 + wn * 32 + j * 16 + l16;
            int rbase = m0 + wm * 32 + i * 16 + quad * 4;
#pragma unroll
            for (int rr = 0; rr < 4; rr++) {
                int row = rbase + rr;
                float vv = acc[i][j][rr];
                if constexpr (EPI == 5)
                    atomicAdd(&C[(size_t)row * ldc + col], vv);
                else
                    C[(size_t)row * ldc + col] = (OutT)f2bf(vv);
            }
        }
}

// fused q / kv_v / kv_a projections (all K=1024, bf16 out), 80 blocks
struct GSeg {
    const ushort_t* A; const ushort_t* B; ushort_t* C;
    int lda, ldb, ldc, nx, start;
};
__global__ __launch_bounds__(256) void gemm64_multi(GSeg s0, GSeg s1, GSeg s2,
                                                    int K) {
    __shared__ ushort_t As[64 * 40];
    __shared__ ushort_t Bs[64 * 40];
    int id = blockIdx.x;
    GSeg s = (id >= s2.start) ? s2 : ((id >= s1.start) ? s1 : s0);
    int t = id - s.start;
    gemm_item<0, ushort_t>(s.A, s.lda, s.B, s.ldb, s.C, s.ldc, K,
                           (t / s.nx) * 64, (t % s.nx) * 64, As, Bs);
}

// mlp2: split-K=4, atomicAdd into outp (pre-initialized to y+b2 by proj)
__global__ __launch_bounds__(256) void gemm_mlp2(const ushort_t* __restrict__ g,
                                                 const ushort_t* __restrict__ W2t,
                                                 float* __restrict__ outp) {
    __shared__ ushort_t As[64 * 40];
    __shared__ ushort_t Bs[64 * 40];
    int z = blockIdx.z;
    gemm_item<5, float>(g + z * 1024, 4096, W2t + z * 1024, 4096, outp, 1024,
                        1024, blockIdx.y * 64, blockIdx.x * 64, As, Bs);
}

// ---------------------------------------------------------------------------
// proj: y = attnout @ Wproj + bproj + xmm  (fp32), K=256.
// Also: outp = y + b2 (init for mlp2 atomics) and per-row sum/sumsq atomics
// into stats[1024] (for the fused LN in mlp1).
// grid (16 n-tiles, 8 m-tiles).
// ---------------------------------------------------------------------------
__global__ __launch_bounds__(256) void gemm_proj(
    const ushort_t* __restrict__ A, const ushort_t* __restrict__ Bt,
    const float* __restrict__ bproj, const float* __restrict__ xmm,
    const float* __restrict__ b2, float* __restrict__ y,
    float* __restrict__ outp, float* __restrict__ stats) {
    constexpr int LS = 40;
    __shared__ ushort_t As[64 * LS];
    __shared__ ushort_t Bs[64 * LS];
    int tid = threadIdx.x;
    int wave = tid >> 6, lane = tid & 63;
    int wm = wave >> 1, wn = wave & 1;
    int quad = lane >> 4, l16 = lane & 15;
    int m0 = blockIdx.y * 64, n0 = blockIdx.x * 64;

    f32x4 acc[2][2];
#pragma unroll
    for (int i = 0; i < 2; i++)
#pragma unroll
        for (int j = 0; j < 2; j++) acc[i][j] = (f32x4){0.f, 0.f, 0.f, 0.f};

    int r = tid >> 2, c = tid & 3;
    const ushort_t* Ap = A + (size_t)(m0 + r) * 256 + c * 8;
    const ushort_t* Bp = Bt + (size_t)(n0 + r) * 256 + c * 8;
    uint4 ra = *(const uint4*)Ap;
    uint4 rb = *(const uint4*)Bp;

    for (int k0 = 0; k0 < 256; k0 += 32) {
        *(uint4*)(&As[r * LS + c * 8]) = ra;
        *(uint4*)(&Bs[r * LS + c * 8]) = rb;
        __syncthreads();
        if (k0 + 32 < 256) {
            ra = *(const uint4*)(Ap + k0 + 32);
            rb = *(const uint4*)(Bp + k0 + 32);
        }
        bf16x8 af[2], bfr[2];
#pragma unroll
        for (int i = 0; i < 2; i++)
            af[i] = *(const bf16x8*)(&As[(wm * 32 + i * 16 + l16) * LS + quad * 8]);
#pragma unroll
        for (int j = 0; j < 2; j++)
            bfr[j] = *(const bf16x8*)(&Bs[(wn * 32 + j * 16 + l16) * LS + quad * 8]);
#pragma unroll
        for (int i = 0; i < 2; i++)
#pragma unroll
            for (int j = 0; j < 2; j++)
                acc[i][j] = __builtin_amdgcn_mfma_f32_16x16x32_bf16(
                    af[i], bfr[j], acc[i][j], 0, 0, 0);
        __syncthreads();
    }

    float rs[2][4] = {{0.f, 0.f, 0.f, 0.f}, {0.f, 0.f, 0.f, 0.f}};
    float rq[2][4] = {{0.f, 0.f, 0.f, 0.f}, {0.f, 0.f, 0.f, 0.f}};
#pragma unroll
    for (int i = 0; i < 2; i++)
#pragma unroll
        for (int j = 0; j < 2; j++) {
            int col = n0 + wn * 32 + j * 16 + l16;
            int rbase = m0 + wm * 32 + i * 16 + quad * 4;
            float bv = bproj[col];
            float b2v = b2[col];
#pragma unroll
            for (int rr = 0; rr < 4; rr++) {
                int row = rbase + rr;
                float vv = acc[i][j][rr] + bv + xmm[(size_t)row * 1024 + col];
                y[(size_t)row * 1024 + col] = vv;
                outp[(size_t)row * 1024 + col] = vv + b2v;
                rs[i][rr] += vv;
                rq[i][rr] += vv * vv;
            }
        }
    // cross-l16 reduce (bits 0..3 of lane) then one atomic per (wave,row)
#pragma unroll
    for (int i = 0; i < 2; i++)
#pragma unroll
        for (int rr = 0; rr < 4; rr++) {
            float s = rs[i][rr], q = rq[i][rr];
            s += __shfl_xor(s, 1); q += __shfl_xor(q, 1);
            s += __shfl_xor(s, 2); q += __shfl_xor(q, 2);
            s += __shfl_xor(s, 4); q += __shfl_xor(q, 4);
            s += __shfl_xor(s, 8); q += __shfl_xor(q, 8);
            if (l16 == 0) {
                int row = m0 + wm * 32 + i * 16 + quad * 4 + rr;
                atomicAdd(&stats[row], s);
                atomicAdd(&stats[512 + row], q);
            }
        }
}

// ---------------------------------------------------------------------------
// mlp1: g = gelu(LN(y) @ W1 + b1), LN applied inline during A-staging using
// stats (sum, sumsq) accumulated by proj. K=1024, grid (64 n, 8 m).
// ---------------------------------------------------------------------------
__global__ __launch_bounds__(256) void gemm_mlp1(
    const float* __restrict__ y, const float* __restrict__ lnw,
    const float* __restrict__ lnb, const float* __restrict__ stats,
    const ushort_t* __restrict__ W1t, const float* __restrict__ b1,
    ushort_t* __restrict__ g) {
    constexpr int LS = 40;
    __shared__ ushort_t As[64 * LS];
    __shared__ ushort_t Bs[64 * LS];
    int tid = threadIdx.x;
    int wave = tid >> 6, lane = tid & 63;
    int wm = wave >> 1, wn = wave & 1;
    int quad = lane >> 4, l16 = lane & 15;
    int m0 = blockIdx.y * 64, n0 = blockIdx.x * 64;

    f32x4 acc[2][2];
#pragma unroll
    for (int i = 0; i < 2; i++)
#pragma unroll
        for (int j = 0; j < 2; j++) acc[i][j] = (f32x4){0.f, 0.f, 0.f, 0.f};

    int r = tid >> 2, c = tid & 3;
    int rowm = m0 + r;
    float s = stats[rowm], ss = stats[512 + rowm];
    float mean = s * (1.f / 1024.f);
    float rstd = rsqrtf(ss * (1.f / 1024.f) - mean * mean + 1e-5f);

    const float* yp = y + (size_t)rowm * 1024 + c * 8;
    const float* wp = lnw + c * 8;
    const float* bp = lnb + c * 8;
    const ushort_t* Bp = W1t + (size_t)(n0 + r) * 1024 + c * 8;
    float4 y0 = *(const float4*)yp, y1 = *(const float4*)(yp + 4);
    float4 w0 = *(const float4*)wp, w1 = *(const float4*)(wp + 4);
    float4 b0 = *(const float4*)bp, b1v = *(const float4*)(bp + 4);
    uint4 rb = *(const uint4*)Bp;

    for (int k0 = 0; k0 < 1024; k0 += 32) {
        union { ushort_t u[8]; uint4 v; } pa;
        pa.u[0] = f2bf((y0.x - mean) * rstd * w0.x + b0.x);
        pa.u[1] = f2bf((y0.y - mean) * rstd * w0.y + b0.y);
        pa.u[2] = f2bf((y0.z - mean) * rstd * w0.z + b0.z);
        pa.u[3] = f2bf((y0.w - mean) * rstd * w0.w + b0.w);
        pa.u[4] = f2bf((y1.x - mean) * rstd * w1.x + b1v.x);
        pa.u[5] = f2bf((y1.y - mean) * rstd * w1.y + b1v.y);
        pa.u[6] = f2bf((y1.z - mean) * rstd * w1.z + b1v.z);
        pa.u[7] = f2bf((y1.w - mean) * rstd * w1.w + b1v.w);
        *(uint4*)(&As[r * LS + c * 8]) = pa.v;
        *(uint4*)(&Bs[r * LS + c * 8]) = rb;
        __syncthreads();
        if (k0 + 32 < 1024) {
            y0 = *(const float4*)(yp + k0 + 32);
            y1 = *(const float4*)(yp + k0 + 36);
            w0 = *(const float4*)(wp + k0 + 32);
            w1 = *(const float4*)(wp + k0 + 36);
            b0 = *(const float4*)(bp + k0 + 32);
            b1v = *(const float4*)(bp + k0 + 36);
            rb = *(const uint4*)(Bp + k0 + 32);
        }
        bf16x8 af[2], bfr[2];
#pragma unroll
        for (int i = 0; i < 2; i++)
            af[i] = *(const bf16x8*)(&As[(wm * 32 + i * 16 + l16) * LS + quad * 8]);
#pragma unroll
        for (int j = 0; j < 2; j++)
            bfr[j] = *(const bf16x8*)(&Bs[(wn * 32 + j * 16 + l16) * LS + quad * 8]);
#pragma unroll
        for (int i = 0; i < 2; i++)
#pragma unroll
            for (int j = 0; j < 2; j++)
                acc[i][j] = __builtin_amdgcn_mfma_f32_16x16x32_bf16(
                    af[i], bfr[j], acc[i][j], 0, 0, 0);
        __syncthreads();
    }

#pragma unroll
    for (int i = 0; i < 2; i++)
#pragma unroll
        for (int j = 0; j < 2; j++) {
            int col = n0 + wn * 32 + j * 16 + l16;
            int rbase = m0 + wm * 32 + i * 16 + quad * 4;
            float bv = b1[col];
#pragma unroll
            for (int rr = 0; rr < 4; rr++) {
                int row = rbase + rr;
                float vv = acc[i][j][rr] + bv;
                vv = 0.5f * vv * (1.f + erff(vv * 0.70710678118654752f));
                g[(size_t)row * 4096 + col] = f2bf(vv);
            }
        }
}

// ---------------------------------------------------------------------------
// Factorized attention. Block = 256 threads: 64 q-rows x 4 dim-groups.
// grid (B*H=32, 4 q-chunks). Single-pass softmax (|s| bounded, no overflow).
// ---------------------------------------------------------------------------
__global__ __launch_bounds__(256) void attn_kernel(
    const ushort_t* __restrict__ q, const ushort_t* __restrict__ kvv,
    const ushort_t* __restrict__ kva, ushort_t* __restrict__ out) {
    int bh = blockIdx.x;
    int b = bh >> 4, h = bh & 15;
    int tid = threadIdx.x;

    __shared__ float Kv[64][16], Vv[64][16], Ka[128][16], Va[128][16];
    {
        int row = tid >> 2, seg = (tid >> 1) & 1, half = tid & 1;
        const ushort_t* src =
            kvv + (size_t)(b * 64 + row) * 512 + seg * 256 + h * 16 + half * 8;
        float* dst = (seg ? Vv[row] : Kv[row]) + half * 8;
        unpack8(*(const uint4*)src, dst);
    }
#pragma unroll
    for (int t2 = 0; t2 < 2; t2++) {
        int t = tid + t2 * 256;
        int row = t >> 2, seg = (t >> 1) & 1, half = t & 1;
        const ushort_t* src =
            kva + (size_t)(b * 128 + row) * 512 + seg * 256 + h * 16 + half * 8;
        float* dst = (seg ? Va[row] : Ka[row]) + half * 8;
        unpack8(*(const uint4*)src, dst);
    }
    __syncthreads();

    int qlocal = tid >> 2;
    int dg = tid & 3;
    int qrow = blockIdx.y * 64 + qlocal;
    const ushort_t* qp = q + (size_t)(b * 256 + qrow) * 256 + h * 16 + dg * 4;
    uint2 qu = *(const uint2*)qp;
    float4 qv;
    qv.x = __uint_as_float(qu.x << 16) * 0.125f;
    qv.y = __uint_as_float(qu.x & 0xFFFF0000u) * 0.125f;
    qv.z = __uint_as_float(qu.y << 16) * 0.125f;
    qv.w = __uint_as_float(qu.y & 0xFFFF0000u) * 0.125f;

    const float4* Kv4 = (const float4*)Kv;
    const float4* Vv4 = (const float4*)Vv;
    const float4* Ka4 = (const float4*)Ka;
    const float4* Va4 = (const float4*)Va;

    float4 ov = {0.f, 0.f, 0.f, 0.f};
    float den = 0.f;
#pragma unroll 8
    for (int i = 0; i < 64; i++) {
        float4 kk = Kv4[i * 4 + dg];
        float part = qv.x * kk.x + qv.y * kk.y + qv.z * kk.z + qv.w * kk.w;
        part += __shfl_xor(part, 1);
        part += __shfl_xor(part, 2);
        float pe = __expf(part);
        den += pe;
        float4 vv = Vv4[i * 4 + dg];
        ov.x += pe * vv.x; ov.y += pe * vv.y;
        ov.z += pe * vv.z; ov.w += pe * vv.w;
    }
    float4 oa = {0.f, 0.f, 0.f, 0.f};
    float dena = 0.f;
#pragma unroll 8
    for (int i = 0; i < 128; i++) {
        float4 kk = Ka4[i * 4 + dg];
        float part = qv.x * kk.x + qv.y * kk.y + qv.z * kk.z + qv.w * kk.w;
        part += __shfl_xor(part, 1);
        part += __shfl_xor(part, 2);
        float pe = __expf(part);
        dena += pe;
        float4 vv = Va4[i * 4 + dg];
        oa.x += pe * vv.x; oa.y += pe * vv.y;
        oa.z += pe * vv.z; oa.w += pe * vv.w;
    }

    float rv = 1.f / den, ra = 1.f / dena;
    union { ushort_t u[4]; uint2 v; } pk;
    pk.u[0] = f2bf(ov.x * rv + oa.x * ra);
    pk.u[1] = f2bf(ov.y * rv + oa.y * ra);
    pk.u[2] = f2bf(ov.z * rv + oa.z * ra);
    pk.u[3] = f2bf(ov.w * rv + oa.w * ra);
    *(uint2*)(out + (size_t)(b * 256 + qrow) * 256 + h * 16 + dg * 4) = pk.v;
}

// ---------------------------------------------------------------------------
extern "C" void kernel_launch(void* const* d_in, const int* in_sizes, int n_in,
                              void* d_out, int out_size, void* d_ws,
                              size_t ws_size, hipStream_t stream) {
    const float* xmm = (const float*)d_in[0];
    const float* xv = (const float*)d_in[1];
    const float* xa = (const float*)d_in[2];
    const float* ln_mm_w = (const float*)d_in[3];
    const float* ln_mm_b = (const float*)d_in[4];
    const float* ln_v_w = (const float*)d_in[5];
    const float* ln_v_b = (const float*)d_in[6];
    const float* ln_a_w = (const float*)d_in[7];
    const float* ln_a_b = (const float*)d_in[8];
    const float* Wq = (const float*)d_in[9];
    const float* Wkv = (const float*)d_in[10];
    const float* Wproj = (const float*)d_in[11];
    const float* bproj = (const float*)d_in[12];
    const float* ln_mlp_w = (const float*)d_in[13];
    const float* ln_mlp_b = (const float*)d_in[14];
    const float* W1 = (const float*)d_in[15];
    const float* b1 = (const float*)d_in[16];
    const float* W2 = (const float*)d_in[17];
    const float* b2 = (const float*)d_in[18];
    float* outp = (float*)d_out;

    char* w = (char*)d_ws;
    ushort_t* xmmN = (ushort_t*)w;    w += 512 * 1024 * 2;
    ushort_t* xvN = (ushort_t*)w;     w += 128 * 1024 * 2;
    ushort_t* xaN = (ushort_t*)w;     w += 256 * 1024 * 2;
    ushort_t* Wqt = (ushort_t*)w;     w += 256 * 1024 * 2;
    ushort_t* Wkvt = (ushort_t*)w;    w += 512 * 2048 * 2;
    ushort_t* Wprojt = (ushort_t*)w;  w += 1024 * 256 * 2;
    ushort_t* W1t = (ushort_t*)w;     w += 4096 * 1024 * 2;
    ushort_t* W2t = (ushort_t*)w;     w += 1024 * 4096 * 2;
    ushort_t* qout = (ushort_t*)w;    w += 512 * 256 * 2;
    ushort_t* kvvb = (ushort_t*)w;    w += 128 * 512 * 2;
    ushort_t* kvab = (ushort_t*)w;    w += 256 * 512 * 2;
    ushort_t* attnout = (ushort_t*)w; w += 512 * 256 * 2;
    float* y = (float*)w;             w += 512 * 1024 * 4;
    ushort_t* g = (ushort_t*)w;       w += 512 * 4096 * 2;
    float* stats = (float*)w;         w += 1024 * 4;

    // 1) prep: 3 LNs + 5 transposes + zero stats
    LNSeg L0{xmm, ln_mm_w, ln_mm_b, xmmN, 0};
    LNSeg L1{xv, ln_v_w, ln_v_b, xvN, 512};
    LNSeg L2{xa, ln_a_w, ln_a_b, xaN, 640};
    TDesc T0{Wq, Wqt, 1024, 256, 8, 0};
    TDesc T1{Wkv, Wkvt, 2048, 512, 16, 256};
    TDesc T2{Wproj, Wprojt, 256, 1024, 32, 1280};
    TDesc T3{W1, W1t, 1024, 4096, 128, 1536};
    TDesc T4{W2, W2t, 4096, 1024, 32, 5632};
    prep_kernel<<<896 + 9728, 256, 0, stream>>>(L0, L1, L2, T0, T1, T2, T3,
                                                T4, stats);

    // 2) q / kv_v / kv_a projections (80 blocks)
    GSeg G0{xmmN, Wqt, qout, 1024, 1024, 256, 4, 0};
    GSeg G1{xvN, Wkvt, kvvb, 1024, 2048, 512, 8, 32};
    GSeg G2{xaN, Wkvt + 1024, kvab, 1024, 2048, 512, 8, 48};
    gemm64_multi<<<80, 256, 0, stream>>>(G0, G1, G2, 1024);

    // 3) factorized attention
    attn_kernel<<<dim3(32, 4), 256, 0, stream>>>(qout, kvvb, kvab, attnout);

    // 4) proj (+ outp init + LN stats)
    gemm_proj<<<dim3(16, 8), 256, 0, stream>>>(attnout, Wprojt, bproj, xmm,
                                               b2, y, outp, stats);

    // 5) mlp1 with inline LN
    gemm_mlp1<<<dim3(64, 8), 256, 0, stream>>>(y, ln_mlp_w, ln_mlp_b, stats,
                                               W1t, b1, g);

    // 6) mlp2 split-K=4, atomic accumulate into outp
    gemm_mlp2<<<dim3(16, 8, 4), 256, 0, stream>>>(g, W2t, outp);

    (void)in_sizes; (void)n_in; (void)out_size; (void)ws_size;
}